// Round 5
// baseline (937.453 us; speedup 1.0000x reference)
//
#include <hip/hip_runtime.h>
#include <math.h>

#define S_ 2048
#define C_ 512
#define H_ 16
#define D_ 32
#define B_ 2
#define M_ (B_ * S_)
#define RSCALE 0.04419417382415922f  // 1/sqrt(512)

typedef __attribute__((ext_vector_type(8))) short bf16x8;
typedef __attribute__((ext_vector_type(4))) float f32x4;

__device__ inline unsigned short f2bf(float f) {
  unsigned u = __builtin_bit_cast(unsigned, f);
  u += 0x7FFFu + ((u >> 16) & 1u);
  return (unsigned short)(u >> 16);
}

// ---------------- GEMM: O = X @ W^T (+bias), epilogue per mode ----------------
// mode 0: fp32 [M][C] (+bias)           -> Of
// mode 1: bf16 QU/QV [B][H][S][D], (+bias+bias2)*RSCALE / (+bias+bias3)*RSCALE
// mode 2: bf16 [B][H][S][D] (+bias if non-null)              -> Ob   (K, POS)
// mode 3: bf16 [B][H][D][S] transposed (+bias)               -> Ob   (V)
__global__ __launch_bounds__(256) void gemm_xwT(
    const float* __restrict__ X, const float* __restrict__ W,
    const float* __restrict__ bias, const float* __restrict__ bias2,
    const float* __restrict__ bias3, float* __restrict__ Of,
    short* __restrict__ Ob, short* __restrict__ Ob2, int mode) {
  __shared__ __align__(16) float As[16][64];
  __shared__ __align__(16) float Bs[16][64];
  const int tid = threadIdx.x;
  const int bm = blockIdx.y * 64;
  const int bn = blockIdx.x * 64;
  const int tm = (tid >> 4) * 4;
  const int tn = (tid & 15) * 4;
  const int lr = tid >> 2;
  const int lc = (tid & 3) * 4;
  float acc[4][4] = {};
  const float* Xp = X + (size_t)(bm + lr) * C_ + lc;
  const float* Wp = W + (size_t)(bn + lr) * C_ + lc;
  for (int k0 = 0; k0 < C_; k0 += 16) {
    float4 a = *(const float4*)(Xp + k0);
    float4 b = *(const float4*)(Wp + k0);
    __syncthreads();
    As[lc + 0][lr] = a.x; As[lc + 1][lr] = a.y; As[lc + 2][lr] = a.z; As[lc + 3][lr] = a.w;
    Bs[lc + 0][lr] = b.x; Bs[lc + 1][lr] = b.y; Bs[lc + 2][lr] = b.z; Bs[lc + 3][lr] = b.w;
    __syncthreads();
#pragma unroll
    for (int k = 0; k < 16; ++k) {
      float av[4], bv[4];
      *(float4*)av = *(const float4*)&As[k][tm];
      *(float4*)bv = *(const float4*)&Bs[k][tn];
#pragma unroll
      for (int i = 0; i < 4; ++i)
#pragma unroll
        for (int j = 0; j < 4; ++j) acc[i][j] += av[i] * bv[j];
    }
  }
  const int col0 = bn + tn;
  const int row0 = bm + tm;
  if (mode == 0) {
#pragma unroll
    for (int i = 0; i < 4; ++i) {
#pragma unroll
      for (int j = 0; j < 4; ++j)
        Of[(size_t)(row0 + i) * C_ + col0 + j] = acc[i][j] + (bias ? bias[col0 + j] : 0.0f);
    }
  } else if (mode == 1) {
    const int h = col0 >> 5, d0 = col0 & 31;
#pragma unroll
    for (int i = 0; i < 4; ++i) {
      const int row = row0 + i;
      const int bb = row >> 11, s = row & (S_ - 1);
      const size_t base = ((size_t)(bb * H_ + h) * S_ + s) * D_ + d0;
      ushort4 qu, qv;
      unsigned short* pu = (unsigned short*)&qu;
      unsigned short* pv = (unsigned short*)&qv;
#pragma unroll
      for (int j = 0; j < 4; ++j) {
        const float val = acc[i][j] + bias[col0 + j];
        pu[j] = f2bf((val + bias2[col0 + j]) * RSCALE);
        pv[j] = f2bf((val + bias3[col0 + j]) * RSCALE);
      }
      *(ushort4*)(Ob + base) = qu;
      *(ushort4*)(Ob2 + base) = qv;
    }
  } else if (mode == 2) {
    const int h = col0 >> 5, d0 = col0 & 31;
#pragma unroll
    for (int i = 0; i < 4; ++i) {
      const int row = row0 + i;
      const int bb = row >> 11, s = row & (S_ - 1);
      const size_t base = ((size_t)(bb * H_ + h) * S_ + s) * D_ + d0;
      ushort4 kv;
      unsigned short* pk = (unsigned short*)&kv;
#pragma unroll
      for (int j = 0; j < 4; ++j)
        pk[j] = f2bf(acc[i][j] + (bias ? bias[col0 + j] : 0.0f));
      *(ushort4*)(Ob + base) = kv;
    }
  } else {  // mode 3: transposed [B][H][D][S]
    const int bb = row0 >> 11, s0 = row0 & (S_ - 1);
#pragma unroll
    for (int j = 0; j < 4; ++j) {
      const int colj = col0 + j;
      const int h = colj >> 5, d = colj & 31;
      const float bb_ = bias ? bias[colj] : 0.0f;
      ushort4 vv;
      unsigned short* pvv = (unsigned short*)&vv;
#pragma unroll
      for (int i = 0; i < 4; ++i) pvv[i] = f2bf(acc[i][j] + bb_);
      *(ushort4*)(Ob + ((size_t)(bb * H_ + h) * D_ + d) * S_ + s0) = vv;
    }
  }
}

// ---------------- Fused relative attention, MFMA flash ----------------
// 1-D grid of 1024 blocks, XCD-swizzled: xcd = blk&7 owns 4 heads (L2 locality).
// Bands A (u<=0) and B (u>=2) write disjoint predicated columns of one PB
// buffer (A: cc <= 63-dnm, B: cc >= 65-dnm; u==1 never written or read),
// so one barrier covers both. 3 barriers per chunk.
__global__ __launch_bounds__(256, 4) void attn_mfma(
    const short* __restrict__ QU, const short* __restrict__ QV,
    const short* __restrict__ Kb, const short* __restrict__ Vt,
    const short* __restrict__ POSb, float* __restrict__ CTX) {
  __shared__ float PB[64 * 128];   // 32 KB band buffer (swizzled cols)
  __shared__ short Pl[64 * 64];    // 8 KB P tile bf16 (swizzled cols)
  const int tid = threadIdx.x;
  const int w = tid >> 6;
  const int lane = tid & 63;
  const int col = lane & 15;
  const int quad = lane >> 4;
  const int blk = blockIdx.x;
  const int xcd = blk & 7;
  const int i = blk >> 3;
  const int bh = xcd * 4 + (i >> 5);   // 4 heads per XCD
  const int mb = i & 31;
  const int m0 = mb * 64;
  const int b = bh >> 4, h = bh & 15;

  const short* QUh = QU + (size_t)bh * S_ * D_;
  const short* QVh = QV + (size_t)bh * S_ * D_;
  const short* Kh = Kb + (size_t)bh * S_ * D_;
  const short* Vh = Vt + (size_t)bh * D_ * S_;
  const short* Ph = POSb + (size_t)bh * S_ * D_;

  // Persistent A-fragments (A[m=lane&15][k=quad*8+j])
  const int arow = m0 + 16 * w + col;
  const bf16x8 aQU = *(const bf16x8*)(QUh + (size_t)arow * D_ + quad * 8);
  const bf16x8 aQVA = *(const bf16x8*)(QVh + (size_t)arow * D_ + quad * 8);
  const int arowB = (arow + 1 < S_) ? (arow + 1) : (S_ - 1);  // row S-1 result unused
  const bf16x8 aQVB = *(const bf16x8*)(QVh + (size_t)arowB * D_ + quad * 8);

  const f32x4 zc = {0.f, 0.f, 0.f, 0.f};
  f32x4 ctxa0 = zc, ctxa1 = zc;
  float lpart[4] = {0.f, 0.f, 0.f, 0.f};
  const int mi0 = 16 * w + 4 * quad;
  const int swz0 = ((mi0 & 4) << 2) ^ ((mi0 & 3) << 3);  // swz(mi0+r) = swz0 ^ (r<<3) for r<4

  for (int ch = 0; ch < 32; ++ch) {
    const int n0 = ch * 64;
    const int dnm = n0 - m0;
    const bool bandA = (dnm <= 63);
    const bool bandB = (dnm >= -61);
    // ---- phase 0: issue global loads before the barrier ----
    bf16x8 bk[4];
#pragma unroll
    for (int j = 0; j < 4; ++j)
      bk[j] = *(const bf16x8*)(Kh + (size_t)(n0 + 16 * j + col) * D_ + quad * 8);
    bf16x8 bpA[8];
    if (bandA) {
      const int tA0 = S_ - 64 + dnm;
#pragma unroll
      for (int j = 0; j < 8; ++j) {
        int t = tA0 + 16 * j + col;
        if (t > S_ - 1) t = S_ - 1;  // clamp; value discarded by write predicate
        bpA[j] = *(const bf16x8*)(Ph + (size_t)t * D_ + quad * 8);
      }
    }
    __syncthreads();  // B1: prev chunk's PB gathers + Pl PV-reads done
    // ---- phase 1: band MFMAs + predicated disjoint PB writes ----
    if (bandA) {
#pragma unroll
      for (int j = 0; j < 8; ++j) {
        f32x4 c = __builtin_amdgcn_mfma_f32_16x16x32_bf16(aQVA, bpA[j], zc, 0, 0, 0);
        const int cc = 16 * j + col;
        if (cc <= 63 - dnm) {
#pragma unroll
          for (int r = 0; r < 4; ++r)
            PB[(mi0 + r) * 128 + (cc ^ (swz0 ^ (r << 3)))] = c[r];
        }
      }
    }
    if (bandB) {
      const int tB0 = dnm - 65;
#pragma unroll
      for (int j = 0; j < 8; ++j) {
        int t = tB0 + 16 * j + col;
        if (t < 0) t = 0;  // clamp; value discarded by write predicate
        bf16x8 bp = *(const bf16x8*)(Ph + (size_t)t * D_ + quad * 8);
        f32x4 c = __builtin_amdgcn_mfma_f32_16x16x32_bf16(aQVB, bp, zc, 0, 0, 0);
        const int cc = 16 * j + col;
        if (cc >= 65 - dnm) {
#pragma unroll
          for (int r = 0; r < 4; ++r)
            PB[(mi0 + r) * 128 + (cc ^ (swz0 ^ (r << 3)))] = c[r];
        }
      }
    }
    // content scores (register-only, pre-scaled by RSCALE)
    f32x4 sc[4];
#pragma unroll
    for (int j = 0; j < 4; ++j)
      sc[j] = __builtin_amdgcn_mfma_f32_16x16x32_bf16(aQU, bk[j], zc, 0, 0, 0);
    __syncthreads();  // B2: PB ready
    // ---- phase 2: V loads (latency overlap), gathers, exp, Pl writes ----
    bf16x8 bv[4];
#pragma unroll
    for (int k0 = 0; k0 < 2; ++k0) {
      bv[2 * k0] = *(const bf16x8*)(Vh + (size_t)col * S_ + n0 + k0 * 32 + quad * 8);
      bv[2 * k0 + 1] = *(const bf16x8*)(Vh + (size_t)(16 + col) * S_ + n0 + k0 * 32 + quad * 8);
    }
#pragma unroll
    for (int j = 0; j < 4; ++j)
#pragma unroll
      for (int r = 0; r < 4; ++r) {
        const int mi = mi0 + r;
        const int nj = 16 * j + col;
        const int u = dnm + nj - mi;
        if (u <= 0 || u >= 2) {
          const int idx = (nj - mi + 63) ^ (swz0 ^ (r << 3));
          sc[j][r] += PB[mi * 128 + idx];
        }
      }
#pragma unroll
    for (int j = 0; j < 4; ++j)
#pragma unroll
      for (int r = 0; r < 4; ++r) {
        const float p = __expf(sc[j][r]);
        lpart[r] += p;
        const int mi = mi0 + r;
        const int cc = (16 * j + col) ^ ((mi & 7) << 3);
        Pl[mi * 64 + cc] = (short)f2bf(p);
      }
    __syncthreads();  // B3: Pl ready
    // ---- phase 3: PV MFMAs ----
    const int prow = 16 * w + col;
    const int psw = (prow & 7) << 3;
#pragma unroll
    for (int k0 = 0; k0 < 2; ++k0) {
      const bf16x8 ap = *(const bf16x8*)(&Pl[prow * 64 + ((k0 * 32 + quad * 8) ^ psw)]);
      ctxa0 = __builtin_amdgcn_mfma_f32_16x16x32_bf16(ap, bv[2 * k0], ctxa0, 0, 0, 0);
      ctxa1 = __builtin_amdgcn_mfma_f32_16x16x32_bf16(ap, bv[2 * k0 + 1], ctxa1, 0, 0, 0);
    }
  }
  // ---- epilogue ----
#pragma unroll
  for (int r = 0; r < 4; ++r) {
    float s = lpart[r];
    s += __shfl_xor(s, 1);
    s += __shfl_xor(s, 2);
    s += __shfl_xor(s, 4);
    s += __shfl_xor(s, 8);
    lpart[r] = 1.0f / s;
  }
  const int mrow = m0 + mi0;
#pragma unroll
  for (int r = 0; r < 4; ++r) {
    const size_t obase = ((size_t)(b * S_ + mrow + r)) * C_ + h * D_;
    CTX[obase + col] = ctxa0[r] * lpart[r];
    CTX[obase + 16 + col] = ctxa1[r] * lpart[r];
  }
}

extern "C" void kernel_launch(void* const* d_in, const int* in_sizes, int n_in,
                              void* d_out, int out_size, void* d_ws, size_t ws_size,
                              hipStream_t stream) {
  (void)in_sizes; (void)n_in; (void)out_size; (void)ws_size;
  const float* q = (const float*)d_in[0];
  const float* k = (const float*)d_in[1];
  const float* v = (const float*)d_in[2];
  const float* pe = (const float*)d_in[3];
  const float* Wq = (const float*)d_in[4];
  const float* bq = (const float*)d_in[5];
  const float* Wk = (const float*)d_in[6];
  const float* bk = (const float*)d_in[7];
  const float* Wv = (const float*)d_in[8];
  const float* bv = (const float*)d_in[9];
  const float* Wp = (const float*)d_in[10];
  const float* ub = (const float*)d_in[11];
  const float* vb = (const float*)d_in[12];
  const float* Wo = (const float*)d_in[13];
  const float* bo = (const float*)d_in[14];
  float* out = (float*)d_out;

  const size_t MC = (size_t)M_ * C_;
  short* QUb = (short*)d_ws;
  short* QVb = QUb + MC;
  short* Kbb = QVb + MC;
  short* Vtb = Kbb + MC;
  short* POSB = Vtb + MC;
  float* CTX = (float*)(POSB + MC);

  dim3 ggrid(C_ / 64, M_ / 64);
  gemm_xwT<<<ggrid, 256, 0, stream>>>(q, Wq, bq, ub, vb, nullptr, QUb, QVb, 1);
  gemm_xwT<<<ggrid, 256, 0, stream>>>(k, Wk, bk, nullptr, nullptr, nullptr, Kbb, nullptr, 2);
  gemm_xwT<<<ggrid, 256, 0, stream>>>(v, Wv, bv, nullptr, nullptr, nullptr, Vtb, nullptr, 3);
  gemm_xwT<<<ggrid, 256, 0, stream>>>(pe, Wp, nullptr, nullptr, nullptr, nullptr, POSB, nullptr, 2);
  attn_mfma<<<dim3(1024), 256, 0, stream>>>(QUb, QVb, Kbb, Vtb, POSB, CTX);
  gemm_xwT<<<ggrid, 256, 0, stream>>>(CTX, Wo, bo, nullptr, nullptr, out, nullptr, nullptr, 0);
}

// Round 6
// 885.517 us; speedup vs baseline: 1.0586x; 1.0586x over previous
//
#include <hip/hip_runtime.h>
#include <math.h>

#define S_ 2048
#define C_ 512
#define H_ 16
#define D_ 32
#define B_ 2
#define M_ (B_ * S_)
#define RSCALE 0.04419417382415922f  // 1/sqrt(512)

typedef __attribute__((ext_vector_type(8))) short bf16x8;
typedef __attribute__((ext_vector_type(4))) float f32x4;

__device__ inline unsigned short f2bf(float f) {
  unsigned u = __builtin_bit_cast(unsigned, f);
  u += 0x7FFFu + ((u >> 16) & 1u);
  return (unsigned short)(u >> 16);
}

// ---------------- MFMA GEMM with hi/lo bf16 split: O = X @ W^T (+bias) ----------
// Split x = hi + lo (bf16 truncation); acc = hh + hl + lh MFMAs -> ~2^-16 rel acc.
// mode 0: fp32 [M][C] (+bias)                                   -> Of
// mode 1: bf16 QU/QV [B][H][S][D], (+bias+bias2)*RS / (+bias+bias3)*RS -> Ob, Ob2
// mode 2: bf16 [B][H][S][D] (+bias if non-null)                 -> Ob   (K, POS)
// mode 3: bf16 [B][H][D][S] transposed (+bias)                  -> Ob   (V)
__global__ __launch_bounds__(256) void gemm_mfma(
    const float* __restrict__ X, const float* __restrict__ W,
    const float* __restrict__ bias, const float* __restrict__ bias2,
    const float* __restrict__ bias3, float* __restrict__ Of,
    short* __restrict__ Ob, short* __restrict__ Ob2, int mode) {
  __shared__ __align__(16) unsigned short Ah[64][40];
  __shared__ __align__(16) unsigned short Al[64][40];
  __shared__ __align__(16) unsigned short Bh[64][40];
  __shared__ __align__(16) unsigned short Bl[64][40];
  const int tid = threadIdx.x;
  const int w = tid >> 6;
  const int lane = tid & 63;
  const int col = lane & 15;
  const int quad = lane >> 4;
  const int bm = blockIdx.y * 64;
  const int bn = blockIdx.x * 64;
  const int srow = tid >> 2;          // staging row 0..63
  const int skc = (tid & 3) * 8;      // staging k offset 0,8,16,24

  const f32x4 zc = {0.f, 0.f, 0.f, 0.f};
  f32x4 acc[4] = {zc, zc, zc, zc};

  const float* Xp = X + (size_t)(bm + srow) * C_;
  const float* Wp = W + (size_t)(bn + srow) * C_;

  for (int k0 = 0; k0 < C_; k0 += 32) {
    float4 xa = *(const float4*)(Xp + k0 + skc);
    float4 xb = *(const float4*)(Xp + k0 + skc + 4);
    float4 wa = *(const float4*)(Wp + k0 + skc);
    float4 wb = *(const float4*)(Wp + k0 + skc + 4);
    __syncthreads();
    {
      float f[8] = {xa.x, xa.y, xa.z, xa.w, xb.x, xb.y, xb.z, xb.w};
      float g[8] = {wa.x, wa.y, wa.z, wa.w, wb.x, wb.y, wb.z, wb.w};
      unsigned fh[8], fl[8], gh[8], gl[8];
#pragma unroll
      for (int i = 0; i < 8; ++i) {
        unsigned u = __builtin_bit_cast(unsigned, f[i]);
        fh[i] = u & 0xffff0000u;
        fl[i] = __builtin_bit_cast(unsigned, f[i] - __builtin_bit_cast(float, fh[i]));
        unsigned v = __builtin_bit_cast(unsigned, g[i]);
        gh[i] = v & 0xffff0000u;
        gl[i] = __builtin_bit_cast(unsigned, g[i] - __builtin_bit_cast(float, gh[i]));
      }
      uint4 ph, pl, qh, ql;
      ph.x = (fh[0] >> 16) | fh[1];  ph.y = (fh[2] >> 16) | fh[3];
      ph.z = (fh[4] >> 16) | fh[5];  ph.w = (fh[6] >> 16) | fh[7];
      pl.x = (fl[0] >> 16) | (fl[1] & 0xffff0000u);
      pl.y = (fl[2] >> 16) | (fl[3] & 0xffff0000u);
      pl.z = (fl[4] >> 16) | (fl[5] & 0xffff0000u);
      pl.w = (fl[6] >> 16) | (fl[7] & 0xffff0000u);
      qh.x = (gh[0] >> 16) | gh[1];  qh.y = (gh[2] >> 16) | gh[3];
      qh.z = (gh[4] >> 16) | gh[5];  qh.w = (gh[6] >> 16) | gh[7];
      ql.x = (gl[0] >> 16) | (gl[1] & 0xffff0000u);
      ql.y = (gl[2] >> 16) | (gl[3] & 0xffff0000u);
      ql.z = (gl[4] >> 16) | (gl[5] & 0xffff0000u);
      ql.w = (gl[6] >> 16) | (gl[7] & 0xffff0000u);
      *(uint4*)&Ah[srow][skc] = ph;
      *(uint4*)&Al[srow][skc] = pl;
      *(uint4*)&Bh[srow][skc] = qh;
      *(uint4*)&Bl[srow][skc] = ql;
    }
    __syncthreads();
    const bf16x8 ah = *(const bf16x8*)&Ah[16 * w + col][quad * 8];
    const bf16x8 al = *(const bf16x8*)&Al[16 * w + col][quad * 8];
#pragma unroll
    for (int j = 0; j < 4; ++j) {
      const bf16x8 bh = *(const bf16x8*)&Bh[16 * j + col][quad * 8];
      const bf16x8 bl = *(const bf16x8*)&Bl[16 * j + col][quad * 8];
      acc[j] = __builtin_amdgcn_mfma_f32_16x16x32_bf16(ah, bh, acc[j], 0, 0, 0);
      acc[j] = __builtin_amdgcn_mfma_f32_16x16x32_bf16(ah, bl, acc[j], 0, 0, 0);
      acc[j] = __builtin_amdgcn_mfma_f32_16x16x32_bf16(al, bh, acc[j], 0, 0, 0);
    }
  }
  // ---- epilogue: lane holds O[gm = bm+16w+quad*4+r][gn = bn+16j+col] ----
#pragma unroll
  for (int j = 0; j < 4; ++j) {
    const int gn = bn + 16 * j + col;
#pragma unroll
    for (int r = 0; r < 4; ++r) {
      const int gm = bm + 16 * w + quad * 4 + r;
      const float a = acc[j][r];
      if (mode == 0) {
        Of[(size_t)gm * C_ + gn] = a + (bias ? bias[gn] : 0.0f);
      } else if (mode == 1) {
        const int h = gn >> 5, d0 = gn & 31;
        const int bb = gm >> 11, s = gm & (S_ - 1);
        const size_t base = ((size_t)(bb * H_ + h) * S_ + s) * D_ + d0;
        const float val = a + bias[gn];
        Ob[base] = (short)f2bf((val + bias2[gn]) * RSCALE);
        Ob2[base] = (short)f2bf((val + bias3[gn]) * RSCALE);
      } else if (mode == 2) {
        const int h = gn >> 5, d0 = gn & 31;
        const int bb = gm >> 11, s = gm & (S_ - 1);
        Ob[((size_t)(bb * H_ + h) * S_ + s) * D_ + d0] =
            (short)f2bf(a + (bias ? bias[gn] : 0.0f));
      } else {
        const int h = gn >> 5, d0 = gn & 31;
        const int bb = gm >> 11, s = gm & (S_ - 1);
        Ob[((size_t)(bb * H_ + h) * D_ + d0) * S_ + s] =
            (short)f2bf(a + (bias ? bias[gn] : 0.0f));
      }
    }
  }
}

// ---------------- Fused relative attention, MFMA flash ----------------
// Grid (S/64, B*H) — Round-4 proven layout (x = m-tile fastest for L2 reuse).
// Bands A (u<=0) and B (u>=2) write disjoint predicated columns of one PB
// buffer (u==1 never written or read): 3 barriers per chunk.
__global__ __launch_bounds__(256, 4) void attn_mfma(
    const short* __restrict__ QU, const short* __restrict__ QV,
    const short* __restrict__ Kb, const short* __restrict__ Vt,
    const short* __restrict__ POSb, float* __restrict__ CTX) {
  __shared__ float PB[64 * 128];   // 32 KB band buffer (swizzled cols)
  __shared__ short Pl[64 * 64];    // 8 KB P tile bf16 (swizzled cols)
  const int tid = threadIdx.x;
  const int w = tid >> 6;
  const int lane = tid & 63;
  const int col = lane & 15;
  const int quad = lane >> 4;
  const int m0 = blockIdx.x * 64;
  const int bh = blockIdx.y;
  const int b = bh >> 4, h = bh & 15;

  const short* QUh = QU + (size_t)bh * S_ * D_;
  const short* QVh = QV + (size_t)bh * S_ * D_;
  const short* Kh = Kb + (size_t)bh * S_ * D_;
  const short* Vh = Vt + (size_t)bh * D_ * S_;
  const short* Ph = POSb + (size_t)bh * S_ * D_;

  const int arow = m0 + 16 * w + col;
  const bf16x8 aQU = *(const bf16x8*)(QUh + (size_t)arow * D_ + quad * 8);
  const bf16x8 aQVA = *(const bf16x8*)(QVh + (size_t)arow * D_ + quad * 8);
  const int arowB = (arow + 1 < S_) ? (arow + 1) : (S_ - 1);  // row S-1 result unused
  const bf16x8 aQVB = *(const bf16x8*)(QVh + (size_t)arowB * D_ + quad * 8);

  const f32x4 zc = {0.f, 0.f, 0.f, 0.f};
  f32x4 ctxa0 = zc, ctxa1 = zc;
  float lpart[4] = {0.f, 0.f, 0.f, 0.f};
  const int mi0 = 16 * w + 4 * quad;
  const int swz0 = ((mi0 & 4) << 2) ^ ((mi0 & 3) << 3);

  for (int ch = 0; ch < 32; ++ch) {
    const int n0 = ch * 64;
    const int dnm = n0 - m0;
    const bool bandA = (dnm <= 63);
    const bool bandB = (dnm >= -61);
    bf16x8 bk[4];
#pragma unroll
    for (int j = 0; j < 4; ++j)
      bk[j] = *(const bf16x8*)(Kh + (size_t)(n0 + 16 * j + col) * D_ + quad * 8);
    bf16x8 bpA[8];
    if (bandA) {
      const int tA0 = S_ - 64 + dnm;
#pragma unroll
      for (int j = 0; j < 8; ++j) {
        int t = tA0 + 16 * j + col;
        if (t > S_ - 1) t = S_ - 1;  // clamp; discarded by write predicate
        bpA[j] = *(const bf16x8*)(Ph + (size_t)t * D_ + quad * 8);
      }
    }
    __syncthreads();  // B1: prev chunk's PB gathers + Pl PV-reads done
    if (bandA) {
#pragma unroll
      for (int j = 0; j < 8; ++j) {
        f32x4 c = __builtin_amdgcn_mfma_f32_16x16x32_bf16(aQVA, bpA[j], zc, 0, 0, 0);
        const int cc = 16 * j + col;
        if (cc <= 63 - dnm) {
#pragma unroll
          for (int r = 0; r < 4; ++r)
            PB[(mi0 + r) * 128 + (cc ^ (swz0 ^ (r << 3)))] = c[r];
        }
      }
    }
    if (bandB) {
      const int tB0 = dnm - 65;
#pragma unroll
      for (int j = 0; j < 8; ++j) {
        int t = tB0 + 16 * j + col;
        if (t < 0) t = 0;  // clamp; discarded by write predicate
        bf16x8 bp = *(const bf16x8*)(Ph + (size_t)t * D_ + quad * 8);
        f32x4 c = __builtin_amdgcn_mfma_f32_16x16x32_bf16(aQVB, bp, zc, 0, 0, 0);
        const int cc = 16 * j + col;
        if (cc >= 65 - dnm) {
#pragma unroll
          for (int r = 0; r < 4; ++r)
            PB[(mi0 + r) * 128 + (cc ^ (swz0 ^ (r << 3)))] = c[r];
        }
      }
    }
    f32x4 sc[4];
#pragma unroll
    for (int j = 0; j < 4; ++j)
      sc[j] = __builtin_amdgcn_mfma_f32_16x16x32_bf16(aQU, bk[j], zc, 0, 0, 0);
    __syncthreads();  // B2: PB ready
    bf16x8 bv[4];
#pragma unroll
    for (int k0 = 0; k0 < 2; ++k0) {
      bv[2 * k0] = *(const bf16x8*)(Vh + (size_t)col * S_ + n0 + k0 * 32 + quad * 8);
      bv[2 * k0 + 1] = *(const bf16x8*)(Vh + (size_t)(16 + col) * S_ + n0 + k0 * 32 + quad * 8);
    }
#pragma unroll
    for (int j = 0; j < 4; ++j)
#pragma unroll
      for (int r = 0; r < 4; ++r) {
        const int mi = mi0 + r;
        const int nj = 16 * j + col;
        const int u = dnm + nj - mi;
        if (u <= 0 || u >= 2) {
          const int idx = (nj - mi + 63) ^ (swz0 ^ (r << 3));
          sc[j][r] += PB[mi * 128 + idx];
        }
      }
#pragma unroll
    for (int j = 0; j < 4; ++j)
#pragma unroll
      for (int r = 0; r < 4; ++r) {
        const float p = __expf(sc[j][r]);
        lpart[r] += p;
        const int mi = mi0 + r;
        const int cc = (16 * j + col) ^ ((mi & 7) << 3);
        Pl[mi * 64 + cc] = (short)f2bf(p);
      }
    __syncthreads();  // B3: Pl ready
    const int prow = 16 * w + col;
    const int psw = (prow & 7) << 3;
#pragma unroll
    for (int k0 = 0; k0 < 2; ++k0) {
      const bf16x8 ap = *(const bf16x8*)(&Pl[prow * 64 + ((k0 * 32 + quad * 8) ^ psw)]);
      ctxa0 = __builtin_amdgcn_mfma_f32_16x16x32_bf16(ap, bv[2 * k0], ctxa0, 0, 0, 0);
      ctxa1 = __builtin_amdgcn_mfma_f32_16x16x32_bf16(ap, bv[2 * k0 + 1], ctxa1, 0, 0, 0);
    }
  }
#pragma unroll
  for (int r = 0; r < 4; ++r) {
    float s = lpart[r];
    s += __shfl_xor(s, 1);
    s += __shfl_xor(s, 2);
    s += __shfl_xor(s, 4);
    s += __shfl_xor(s, 8);
    lpart[r] = 1.0f / s;
  }
  const int mrow = m0 + mi0;
#pragma unroll
  for (int r = 0; r < 4; ++r) {
    const size_t obase = ((size_t)(b * S_ + mrow + r)) * C_ + h * D_;
    CTX[obase + col] = ctxa0[r] * lpart[r];
    CTX[obase + 16 + col] = ctxa1[r] * lpart[r];
  }
}

extern "C" void kernel_launch(void* const* d_in, const int* in_sizes, int n_in,
                              void* d_out, int out_size, void* d_ws, size_t ws_size,
                              hipStream_t stream) {
  (void)in_sizes; (void)n_in; (void)out_size; (void)ws_size;
  const float* q = (const float*)d_in[0];
  const float* k = (const float*)d_in[1];
  const float* v = (const float*)d_in[2];
  const float* pe = (const float*)d_in[3];
  const float* Wq = (const float*)d_in[4];
  const float* bq = (const float*)d_in[5];
  const float* bk = (const float*)d_in[7];
  const float* Wk = (const float*)d_in[6];
  const float* Wv = (const float*)d_in[8];
  const float* bv = (const float*)d_in[9];
  const float* Wp = (const float*)d_in[10];
  const float* ub = (const float*)d_in[11];
  const float* vb = (const float*)d_in[12];
  const float* Wo = (const float*)d_in[13];
  const float* bo = (const float*)d_in[14];
  float* out = (float*)d_out;

  const size_t MC = (size_t)M_ * C_;
  short* QUb = (short*)d_ws;
  short* QVb = QUb + MC;
  short* Kbb = QVb + MC;
  short* Vtb = Kbb + MC;
  short* POSB = Vtb + MC;
  float* CTX = (float*)(POSB + MC);

  dim3 ggrid(C_ / 64, M_ / 64);
  gemm_mfma<<<ggrid, 256, 0, stream>>>(q, Wq, bq, ub, vb, nullptr, QUb, QVb, 1);
  gemm_mfma<<<ggrid, 256, 0, stream>>>(k, Wk, bk, nullptr, nullptr, nullptr, Kbb, nullptr, 2);
  gemm_mfma<<<ggrid, 256, 0, stream>>>(v, Wv, bv, nullptr, nullptr, nullptr, Vtb, nullptr, 3);
  gemm_mfma<<<ggrid, 256, 0, stream>>>(pe, Wp, nullptr, nullptr, nullptr, nullptr, POSB, nullptr, 2);
  attn_mfma<<<dim3(S_ / 64, B_ * H_), 256, 0, stream>>>(QUb, QVb, Kbb, Vtb, POSB, CTX);
  gemm_mfma<<<ggrid, 256, 0, stream>>>(CTX, Wo, bo, nullptr, nullptr, out, nullptr, nullptr, 0);
}

// Round 7
// 414.971 us; speedup vs baseline: 2.2591x; 2.1339x over previous
//
#include <hip/hip_runtime.h>
#include <math.h>

#define S_ 2048
#define C_ 512
#define H_ 16
#define D_ 32
#define B_ 2
#define M_ (B_ * S_)
#define RSCALE 0.04419417382415922f  // 1/sqrt(512)

typedef __attribute__((ext_vector_type(8))) short bf16x8;
typedef __attribute__((ext_vector_type(4))) float f32x4;

__device__ inline unsigned short f2bf(float f) {
  unsigned u = __builtin_bit_cast(unsigned, f);
  u += 0x7FFFu + ((u >> 16) & 1u);
  return (unsigned short)(u >> 16);
}

// ---------------- MFMA GEMM with hi/lo bf16 split: O = X @ W^T (+bias) ----------
// Split x = hi + lo (bf16 truncation); acc = hh + hl + lh MFMAs -> ~2^-16 rel acc.
// mode 0: fp32 [M][C] (+bias)                                   -> Of
// mode 1: bf16 QU/QV [B][H][S][D], +bias+bias2 / +bias+bias3    -> Ob, Ob2
// mode 2: bf16 [B][H][S][D] (+bias if non-null)                 -> Ob   (K, POS)
// mode 3: bf16 [B][H][D][S] transposed (+bias)                  -> Ob   (V)
__global__ __launch_bounds__(256) void gemm_mfma(
    const float* __restrict__ X, const float* __restrict__ W,
    const float* __restrict__ bias, const float* __restrict__ bias2,
    const float* __restrict__ bias3, float* __restrict__ Of,
    short* __restrict__ Ob, short* __restrict__ Ob2, int mode) {
  __shared__ __align__(16) unsigned short Ah[64][40];
  __shared__ __align__(16) unsigned short Al[64][40];
  __shared__ __align__(16) unsigned short Bh[64][40];
  __shared__ __align__(16) unsigned short Bl[64][40];
  const int tid = threadIdx.x;
  const int w = tid >> 6;
  const int lane = tid & 63;
  const int col = lane & 15;
  const int quad = lane >> 4;
  const int bm = blockIdx.y * 64;
  const int bn = blockIdx.x * 64;
  const int srow = tid >> 2;          // staging row 0..63
  const int skc = (tid & 3) * 8;      // staging k offset 0,8,16,24

  const f32x4 zc = {0.f, 0.f, 0.f, 0.f};
  f32x4 acc[4] = {zc, zc, zc, zc};

  const float* Xp = X + (size_t)(bm + srow) * C_;
  const float* Wp = W + (size_t)(bn + srow) * C_;

  for (int k0 = 0; k0 < C_; k0 += 32) {
    float4 xa = *(const float4*)(Xp + k0 + skc);
    float4 xb = *(const float4*)(Xp + k0 + skc + 4);
    float4 wa = *(const float4*)(Wp + k0 + skc);
    float4 wb = *(const float4*)(Wp + k0 + skc + 4);
    __syncthreads();
    {
      float f[8] = {xa.x, xa.y, xa.z, xa.w, xb.x, xb.y, xb.z, xb.w};
      float g[8] = {wa.x, wa.y, wa.z, wa.w, wb.x, wb.y, wb.z, wb.w};
      unsigned fh[8], fl[8], gh[8], gl[8];
#pragma unroll
      for (int i = 0; i < 8; ++i) {
        unsigned u = __builtin_bit_cast(unsigned, f[i]);
        fh[i] = u & 0xffff0000u;
        fl[i] = __builtin_bit_cast(unsigned, f[i] - __builtin_bit_cast(float, fh[i]));
        unsigned v = __builtin_bit_cast(unsigned, g[i]);
        gh[i] = v & 0xffff0000u;
        gl[i] = __builtin_bit_cast(unsigned, g[i] - __builtin_bit_cast(float, gh[i]));
      }
      uint4 ph, pl, qh, ql;
      ph.x = (fh[0] >> 16) | fh[1];  ph.y = (fh[2] >> 16) | fh[3];
      ph.z = (fh[4] >> 16) | fh[5];  ph.w = (fh[6] >> 16) | fh[7];
      pl.x = (fl[0] >> 16) | (fl[1] & 0xffff0000u);
      pl.y = (fl[2] >> 16) | (fl[3] & 0xffff0000u);
      pl.z = (fl[4] >> 16) | (fl[5] & 0xffff0000u);
      pl.w = (fl[6] >> 16) | (fl[7] & 0xffff0000u);
      qh.x = (gh[0] >> 16) | gh[1];  qh.y = (gh[2] >> 16) | gh[3];
      qh.z = (gh[4] >> 16) | gh[5];  qh.w = (gh[6] >> 16) | gh[7];
      ql.x = (gl[0] >> 16) | (gl[1] & 0xffff0000u);
      ql.y = (gl[2] >> 16) | (gl[3] & 0xffff0000u);
      ql.z = (gl[4] >> 16) | (gl[5] & 0xffff0000u);
      ql.w = (gl[6] >> 16) | (gl[7] & 0xffff0000u);
      *(uint4*)&Ah[srow][skc] = ph;
      *(uint4*)&Al[srow][skc] = pl;
      *(uint4*)&Bh[srow][skc] = qh;
      *(uint4*)&Bl[srow][skc] = ql;
    }
    __syncthreads();
    const bf16x8 ah = *(const bf16x8*)&Ah[16 * w + col][quad * 8];
    const bf16x8 al = *(const bf16x8*)&Al[16 * w + col][quad * 8];
#pragma unroll
    for (int j = 0; j < 4; ++j) {
      const bf16x8 bh = *(const bf16x8*)&Bh[16 * j + col][quad * 8];
      const bf16x8 bl = *(const bf16x8*)&Bl[16 * j + col][quad * 8];
      acc[j] = __builtin_amdgcn_mfma_f32_16x16x32_bf16(ah, bh, acc[j], 0, 0, 0);
      acc[j] = __builtin_amdgcn_mfma_f32_16x16x32_bf16(ah, bl, acc[j], 0, 0, 0);
      acc[j] = __builtin_amdgcn_mfma_f32_16x16x32_bf16(al, bh, acc[j], 0, 0, 0);
    }
  }
  // ---- epilogue: lane holds O[gm = bm+16w+quad*4+r][gn = bn+16j+col] ----
#pragma unroll
  for (int j = 0; j < 4; ++j) {
    const int gn = bn + 16 * j + col;
#pragma unroll
    for (int r = 0; r < 4; ++r) {
      const int gm = bm + 16 * w + quad * 4 + r;
      const float a = acc[j][r];
      if (mode == 0) {
        Of[(size_t)gm * C_ + gn] = a + (bias ? bias[gn] : 0.0f);
      } else if (mode == 1) {
        const int h = gn >> 5, d0 = gn & 31;
        const int bb = gm >> 11, s = gm & (S_ - 1);
        const size_t base = ((size_t)(bb * H_ + h) * S_ + s) * D_ + d0;
        const float val = a + bias[gn];
        Ob[base] = (short)f2bf(val + bias2[gn]);
        Ob2[base] = (short)f2bf(val + bias3[gn]);
      } else if (mode == 2) {
        const int h = gn >> 5, d0 = gn & 31;
        const int bb = gm >> 11, s = gm & (S_ - 1);
        Ob[((size_t)(bb * H_ + h) * S_ + s) * D_ + d0] =
            (short)f2bf(a + (bias ? bias[gn] : 0.0f));
      } else {
        const int h = gn >> 5, d0 = gn & 31;
        const int bb = gm >> 11, s = gm & (S_ - 1);
        Ob[((size_t)(bb * H_ + h) * D_ + d0) * S_ + s] =
            (short)f2bf(a + (bias ? bias[gn] : 0.0f));
      }
    }
  }
}

// ---------------- Fused relative attention, MFMA flash (Round-4 body, verbatim) --
// grid (S/64, B*H), block 256 (4 waves). Wave w owns output rows [16w,16w+16).
__global__ __launch_bounds__(256, 4) void attn_mfma(
    const short* __restrict__ QU, const short* __restrict__ QV,
    const short* __restrict__ Kb, const short* __restrict__ Vt,
    const short* __restrict__ POSb, float* __restrict__ CTX) {
  __shared__ float PB[64 * 128];   // 32 KB band buffer (swizzled cols)
  __shared__ short Pl[64 * 64];    // 8 KB P tile bf16 (swizzled cols)
  const int tid = threadIdx.x;
  const int w = tid >> 6;
  const int lane = tid & 63;
  const int col = lane & 15;
  const int quad = lane >> 4;
  const int m0 = blockIdx.x * 64;
  const int bh = blockIdx.y;
  const int b = bh >> 4, h = bh & 15;

  const short* QUh = QU + (size_t)bh * S_ * D_;
  const short* QVh = QV + (size_t)bh * S_ * D_;
  const short* Kh = Kb + (size_t)bh * S_ * D_;
  const short* Vh = Vt + (size_t)bh * D_ * S_;
  const short* Ph = POSb + (size_t)bh * S_ * D_;

  const int arow = m0 + 16 * w + col;
  const bf16x8 aQU = *(const bf16x8*)(QUh + (size_t)arow * D_ + quad * 8);
  const bf16x8 aQVA = *(const bf16x8*)(QVh + (size_t)arow * D_ + quad * 8);
  const bf16x8 aQVB = *(const bf16x8*)(QVh + (size_t)(arow + 1) * D_ + quad * 8);

  const f32x4 zc = {0.f, 0.f, 0.f, 0.f};
  const bf16x8 zb = {0, 0, 0, 0, 0, 0, 0, 0};
  f32x4 ctxa0 = zc, ctxa1 = zc;
  float lpart[4] = {0.f, 0.f, 0.f, 0.f};
  const int mi0 = 16 * w + 4 * quad;

  for (int ch = 0; ch < 32; ++ch) {
    const int n0 = ch * 64;
    const int dnm = n0 - m0;
    f32x4 sc[4];
#pragma unroll
    for (int j = 0; j < 4; ++j) {
      bf16x8 bk = *(const bf16x8*)(Kh + (size_t)(n0 + 16 * j + col) * D_ + quad * 8);
      sc[j] = __builtin_amdgcn_mfma_f32_16x16x32_bf16(aQU, bk, zc, 0, 0, 0);
    }
    if (dnm <= 63) {
      const int tA0 = S_ - 64 + dnm;
#pragma unroll
      for (int j = 0; j < 8; ++j) {
        const int t = tA0 + 16 * j + col;
        bf16x8 bp = *(const bf16x8*)(Ph + (long)t * D_ + quad * 8);
        if (t >= S_) bp = zb;
        f32x4 c = __builtin_amdgcn_mfma_f32_16x16x32_bf16(aQVA, bp, zc, 0, 0, 0);
#pragma unroll
        for (int r = 0; r < 4; ++r) {
          const int mi = mi0 + r;
          const int cc = (16 * j + col) ^ (((mi & 4) << 2) ^ ((mi & 3) << 3));
          PB[mi * 128 + cc] = c[r];
        }
      }
      __syncthreads();
#pragma unroll
      for (int j = 0; j < 4; ++j)
#pragma unroll
        for (int r = 0; r < 4; ++r) {
          const int mi = mi0 + r;
          const int nj = 16 * j + col;
          if (dnm + nj - mi <= 0) {
            const int idx = (nj - mi + 63) ^ (((mi & 4) << 2) ^ ((mi & 3) << 3));
            sc[j][r] += PB[mi * 128 + idx];
          }
        }
    }
    if (dnm >= -61) {
      __syncthreads();
      const int tB0 = dnm - 65;
#pragma unroll
      for (int j = 0; j < 8; ++j) {
        const int t = tB0 + 16 * j + col;
        bf16x8 bp = *(const bf16x8*)(Ph + (long)t * D_ + quad * 8);
        if (t < 0) bp = zb;
        f32x4 c = __builtin_amdgcn_mfma_f32_16x16x32_bf16(aQVB, bp, zc, 0, 0, 0);
#pragma unroll
        for (int r = 0; r < 4; ++r) {
          const int mi = mi0 + r;
          const int cc = (16 * j + col) ^ (((mi & 4) << 2) ^ ((mi & 3) << 3));
          PB[mi * 128 + cc] = c[r];
        }
      }
      __syncthreads();
#pragma unroll
      for (int j = 0; j < 4; ++j)
#pragma unroll
        for (int r = 0; r < 4; ++r) {
          const int mi = mi0 + r;
          const int nj = 16 * j + col;
          if (dnm + nj - mi >= 2) {
            const int idx = (nj - mi + 63) ^ (((mi & 4) << 2) ^ ((mi & 3) << 3));
            sc[j][r] += PB[mi * 128 + idx];
          }
        }
    }
    __syncthreads();
#pragma unroll
    for (int j = 0; j < 4; ++j)
#pragma unroll
      for (int r = 0; r < 4; ++r) {
        const float p = __expf(sc[j][r] * RSCALE);
        lpart[r] += p;
        const int mi = mi0 + r;
        const int cc = (16 * j + col) ^ ((mi & 7) << 3);
        Pl[mi * 64 + cc] = (short)f2bf(p);
      }
    __syncthreads();
    const int prow = 16 * w + col;
    const int psw = (prow & 7) << 3;
#pragma unroll
    for (int k0 = 0; k0 < 2; ++k0) {
      const bf16x8 ap = *(const bf16x8*)(&Pl[prow * 64 + ((k0 * 32 + quad * 8) ^ psw)]);
      bf16x8 bv0 = *(const bf16x8*)(Vh + (size_t)col * S_ + n0 + k0 * 32 + quad * 8);
      ctxa0 = __builtin_amdgcn_mfma_f32_16x16x32_bf16(ap, bv0, ctxa0, 0, 0, 0);
      bf16x8 bv1 = *(const bf16x8*)(Vh + (size_t)(16 + col) * S_ + n0 + k0 * 32 + quad * 8);
      ctxa1 = __builtin_amdgcn_mfma_f32_16x16x32_bf16(ap, bv1, ctxa1, 0, 0, 0);
    }
  }
#pragma unroll
  for (int r = 0; r < 4; ++r) {
    float s = lpart[r];
    s += __shfl_xor(s, 1);
    s += __shfl_xor(s, 2);
    s += __shfl_xor(s, 4);
    s += __shfl_xor(s, 8);
    lpart[r] = 1.0f / s;
  }
  const int mrow = m0 + mi0;
#pragma unroll
  for (int r = 0; r < 4; ++r) {
    const size_t obase = ((size_t)(b * S_ + mrow + r)) * C_ + h * D_;
    CTX[obase + col] = ctxa0[r] * lpart[r];
    CTX[obase + 16 + col] = ctxa1[r] * lpart[r];
  }
}

extern "C" void kernel_launch(void* const* d_in, const int* in_sizes, int n_in,
                              void* d_out, int out_size, void* d_ws, size_t ws_size,
                              hipStream_t stream) {
  (void)in_sizes; (void)n_in; (void)out_size; (void)ws_size;
  const float* q = (const float*)d_in[0];
  const float* k = (const float*)d_in[1];
  const float* v = (const float*)d_in[2];
  const float* pe = (const float*)d_in[3];
  const float* Wq = (const float*)d_in[4];
  const float* bq = (const float*)d_in[5];
  const float* Wk = (const float*)d_in[6];
  const float* bk = (const float*)d_in[7];
  const float* Wv = (const float*)d_in[8];
  const float* bv = (const float*)d_in[9];
  const float* Wp = (const float*)d_in[10];
  const float* ub = (const float*)d_in[11];
  const float* vb = (const float*)d_in[12];
  const float* Wo = (const float*)d_in[13];
  const float* bo = (const float*)d_in[14];
  float* out = (float*)d_out;

  const size_t MC = (size_t)M_ * C_;
  short* QUb = (short*)d_ws;
  short* QVb = QUb + MC;
  short* Kbb = QVb + MC;
  short* Vtb = Kbb + MC;
  short* POSB = Vtb + MC;
  float* CTX = (float*)(POSB + MC);

  dim3 ggrid(C_ / 64, M_ / 64);
  gemm_mfma<<<ggrid, 256, 0, stream>>>(q, Wq, bq, ub, vb, nullptr, QUb, QVb, 1);
  gemm_mfma<<<ggrid, 256, 0, stream>>>(k, Wk, bk, nullptr, nullptr, nullptr, Kbb, nullptr, 2);
  gemm_mfma<<<ggrid, 256, 0, stream>>>(v, Wv, bv, nullptr, nullptr, nullptr, Vtb, nullptr, 3);
  gemm_mfma<<<ggrid, 256, 0, stream>>>(pe, Wp, nullptr, nullptr, nullptr, nullptr, POSB, nullptr, 2);
  attn_mfma<<<dim3(S_ / 64, B_ * H_), 256, 0, stream>>>(QUb, QVb, Kbb, Vtb, POSB, CTX);
  gemm_mfma<<<ggrid, 256, 0, stream>>>(CTX, Wo, bo, nullptr, nullptr, out, nullptr, nullptr, 0);
}

// Round 8
// 371.148 us; speedup vs baseline: 2.5258x; 1.1181x over previous
//
#include <hip/hip_runtime.h>
#include <math.h>

#define S_ 2048
#define C_ 512
#define H_ 16
#define D_ 32
#define B_ 2
#define M_ (B_ * S_)
#define RSCALE 0.04419417382415922f  // 1/sqrt(512)

typedef __attribute__((ext_vector_type(8))) short bf16x8;
typedef __attribute__((ext_vector_type(4))) float f32x4;

__device__ inline unsigned short f2bf(float f) {
  unsigned u = __builtin_bit_cast(unsigned, f);
  u += 0x7FFFu + ((u >> 16) & 1u);
  return (unsigned short)(u >> 16);
}

// ---------------- split kernels: fp32 -> bf16 hi/lo planes ----------------
__global__ __launch_bounds__(256) void split_x(
    const float* __restrict__ q, const float* __restrict__ k,
    const float* __restrict__ v, const float* __restrict__ pe,
    short* __restrict__ xh, short* __restrict__ xl) {
  const int z = blockIdx.y;
  const float* src = z == 0 ? q : z == 1 ? k : z == 2 ? v : pe;
  const size_t off = (size_t)z * M_ * C_;
  const size_t i = ((size_t)blockIdx.x * 256 + threadIdx.x) * 4;
  float4 f = *(const float4*)(src + i);
  float ff[4] = {f.x, f.y, f.z, f.w};
  ushort4 hv, lv;
  unsigned short* ph = (unsigned short*)&hv;
  unsigned short* pl = (unsigned short*)&lv;
#pragma unroll
  for (int e = 0; e < 4; ++e) {
    unsigned u = __builtin_bit_cast(unsigned, ff[e]);
    unsigned hi = u & 0xffff0000u;
    ph[e] = (unsigned short)(hi >> 16);
    pl[e] = f2bf(ff[e] - __builtin_bit_cast(float, hi));
  }
  *(ushort4*)(xh + off + i) = hv;
  *(ushort4*)(xl + off + i) = lv;
}

__global__ __launch_bounds__(256) void split_w(
    const float* __restrict__ w0, const float* __restrict__ w1,
    const float* __restrict__ w2, const float* __restrict__ w3,
    const float* __restrict__ w4, short* __restrict__ wh,
    short* __restrict__ wl) {
  const int z = blockIdx.y;
  const float* src = z == 0 ? w0 : z == 1 ? w1 : z == 2 ? w2 : z == 3 ? w3 : w4;
  const size_t off = (size_t)z * C_ * C_;
  const size_t i = ((size_t)blockIdx.x * 256 + threadIdx.x) * 4;
  float4 f = *(const float4*)(src + i);
  float ff[4] = {f.x, f.y, f.z, f.w};
  ushort4 hv, lv;
  unsigned short* ph = (unsigned short*)&hv;
  unsigned short* pl = (unsigned short*)&lv;
#pragma unroll
  for (int e = 0; e < 4; ++e) {
    unsigned u = __builtin_bit_cast(unsigned, ff[e]);
    unsigned hi = u & 0xffff0000u;
    ph[e] = (unsigned short)(hi >> 16);
    pl[e] = f2bf(ff[e] - __builtin_bit_cast(float, hi));
  }
  *(ushort4*)(wh + off + i) = hv;
  *(ushort4*)(wl + off + i) = lv;
}

// ---------------- GEMM core: O = (Xh+Xl) @ (Wh+Wl)^T (+bias) ----------------
// Pre-split bf16 hi/lo operands; acc = hh + hl + lh (drops ll ~ 2^-16 rel).
// BK=64, double-buffered LDS (73.7 KB, 2 blocks/CU), 1 barrier/iter.
// Epilogue modes as before.
__device__ __forceinline__ void gemm_core(
    const short* __restrict__ Xh, const short* __restrict__ Xl,
    const short* __restrict__ Wh, const short* __restrict__ Wl,
    const float* bias, const float* bias2, const float* bias3,
    float* __restrict__ Of, short* __restrict__ Ob, short* __restrict__ Ob2,
    int mode) {
  __shared__ __align__(16) short LAh[2][64 * 72];
  __shared__ __align__(16) short LAl[2][64 * 72];
  __shared__ __align__(16) short LBh[2][64 * 72];
  __shared__ __align__(16) short LBl[2][64 * 72];
  const int tid = threadIdx.x;
  const int w = tid >> 6, lane = tid & 63, col = lane & 15, quad = lane >> 4;
  const int bm = blockIdx.y * 64, bn = blockIdx.x * 64;
  const f32x4 zc = {0.f, 0.f, 0.f, 0.f};
  f32x4 acc[4] = {zc, zc, zc, zc};

  uint4 rah[2], ral[2], rbh[2], rbl[2];
  // staging: c = tid + 256*i -> row=c>>3 (0..63), chunk=(c&7)*8 shorts
  const int r0 = tid >> 3, c0 = (tid & 7) * 8;          // i=0
  const int r1 = (tid + 256) >> 3, c1 = c0;             // i=1 (row +32)
#define LOAD_REGS(k0)                                                     \
  {                                                                       \
    rah[0] = *(const uint4*)(Xh + (size_t)(bm + r0) * C_ + (k0) + c0);    \
    ral[0] = *(const uint4*)(Xl + (size_t)(bm + r0) * C_ + (k0) + c0);    \
    rbh[0] = *(const uint4*)(Wh + (size_t)(bn + r0) * C_ + (k0) + c0);    \
    rbl[0] = *(const uint4*)(Wl + (size_t)(bn + r0) * C_ + (k0) + c0);    \
    rah[1] = *(const uint4*)(Xh + (size_t)(bm + r1) * C_ + (k0) + c1);    \
    ral[1] = *(const uint4*)(Xl + (size_t)(bm + r1) * C_ + (k0) + c1);    \
    rbh[1] = *(const uint4*)(Wh + (size_t)(bn + r1) * C_ + (k0) + c1);    \
    rbl[1] = *(const uint4*)(Wl + (size_t)(bn + r1) * C_ + (k0) + c1);    \
  }
#define STORE_LDS(buf)                                                    \
  {                                                                       \
    *(uint4*)&LAh[buf][r0 * 72 + c0] = rah[0];                            \
    *(uint4*)&LAl[buf][r0 * 72 + c0] = ral[0];                            \
    *(uint4*)&LBh[buf][r0 * 72 + c0] = rbh[0];                            \
    *(uint4*)&LBl[buf][r0 * 72 + c0] = rbl[0];                            \
    *(uint4*)&LAh[buf][r1 * 72 + c1] = rah[1];                            \
    *(uint4*)&LAl[buf][r1 * 72 + c1] = ral[1];                            \
    *(uint4*)&LBh[buf][r1 * 72 + c1] = rbh[1];                            \
    *(uint4*)&LBl[buf][r1 * 72 + c1] = rbl[1];                            \
  }
  LOAD_REGS(0)
  STORE_LDS(0)
  for (int it = 0; it < 8; ++it) {
    __syncthreads();  // buf[it&1] ready
    if (it < 7) LOAD_REGS((it + 1) * 64)
    const int buf = it & 1;
#pragma unroll
    for (int ks = 0; ks < 2; ++ks) {
      const int ko = ks * 32 + quad * 8;
      const bf16x8 ah = *(const bf16x8*)&LAh[buf][(16 * w + col) * 72 + ko];
      const bf16x8 al = *(const bf16x8*)&LAl[buf][(16 * w + col) * 72 + ko];
#pragma unroll
      for (int j = 0; j < 4; ++j) {
        const bf16x8 bh = *(const bf16x8*)&LBh[buf][(16 * j + col) * 72 + ko];
        const bf16x8 bl = *(const bf16x8*)&LBl[buf][(16 * j + col) * 72 + ko];
        acc[j] = __builtin_amdgcn_mfma_f32_16x16x32_bf16(ah, bh, acc[j], 0, 0, 0);
        acc[j] = __builtin_amdgcn_mfma_f32_16x16x32_bf16(ah, bl, acc[j], 0, 0, 0);
        acc[j] = __builtin_amdgcn_mfma_f32_16x16x32_bf16(al, bh, acc[j], 0, 0, 0);
      }
    }
    if (it < 7) STORE_LDS(1 - buf)
  }
#undef LOAD_REGS
#undef STORE_LDS
  // ---- epilogue: lane holds O[gm = bm+16w+quad*4+r][gn = bn+16j+col] ----
#pragma unroll
  for (int j = 0; j < 4; ++j) {
    const int gn = bn + 16 * j + col;
#pragma unroll
    for (int r = 0; r < 4; ++r) {
      const int gm = bm + 16 * w + quad * 4 + r;
      const float a = acc[j][r];
      if (mode == 0) {
        Of[(size_t)gm * C_ + gn] = a + (bias ? bias[gn] : 0.0f);
      } else if (mode == 1) {
        const int h = gn >> 5, d0 = gn & 31;
        const int bb = gm >> 11, s = gm & (S_ - 1);
        const size_t base = ((size_t)(bb * H_ + h) * S_ + s) * D_ + d0;
        const float val = a + bias[gn];
        Ob[base] = (short)f2bf(val + bias2[gn]);
        Ob2[base] = (short)f2bf(val + bias3[gn]);
      } else if (mode == 2) {
        const int h = gn >> 5, d0 = gn & 31;
        const int bb = gm >> 11, s = gm & (S_ - 1);
        Ob[((size_t)(bb * H_ + h) * S_ + s) * D_ + d0] =
            (short)f2bf(a + (bias ? bias[gn] : 0.0f));
      } else {
        const int h = gn >> 5, d0 = gn & 31;
        const int bb = gm >> 11, s = gm & (S_ - 1);
        Ob[((size_t)(bb * H_ + h) * D_ + d0) * S_ + s] =
            (short)f2bf(a + (bias ? bias[gn] : 0.0f));
      }
    }
  }
}

// Fused 4-projection launch: z selects {Q->QU/QV, K, V->Vt, POS}.
__global__ __launch_bounds__(256, 2) void proj4(
    const short* __restrict__ XH, const short* __restrict__ XL,
    const short* __restrict__ WH, const short* __restrict__ WL,
    const float* bq, const float* bkk, const float* bvv,
    const float* ub, const float* vb,
    short* QU, short* QV, short* Kb, short* Vt, short* POS) {
  const int z = blockIdx.z;
  const size_t MC = (size_t)M_ * C_, WC = (size_t)C_ * C_;
  const short* xh = XH + z * MC;
  const short* xl = XL + z * MC;
  const short* wh = WH + z * WC;
  const short* wl = WL + z * WC;
  const float* b1 = z == 0 ? bq : z == 1 ? bkk : z == 2 ? bvv : nullptr;
  const int mode = z == 0 ? 1 : z == 2 ? 3 : 2;
  short* ob = z == 0 ? QU : z == 1 ? Kb : z == 2 ? Vt : POS;
  short* ob2 = z == 0 ? QV : nullptr;
  gemm_core(xh, xl, wh, wl, b1, z == 0 ? ub : nullptr, z == 0 ? vb : nullptr,
            nullptr, ob, ob2, mode);
}

__global__ __launch_bounds__(256, 2) void gemm_out(
    const short* __restrict__ CTXh, const short* __restrict__ CTXl,
    const short* __restrict__ WH, const short* __restrict__ WL,
    const float* bo, float* __restrict__ out) {
  const size_t WC = (size_t)C_ * C_;
  gemm_core(CTXh, CTXl, WH + 4 * WC, WL + 4 * WC, bo, nullptr, nullptr,
            out, nullptr, nullptr, 0);
}

// ---------------- Fused relative attention, MFMA flash (R4/R7 body, frozen) ----
// Only the epilogue differs: CTX written as bf16 hi/lo planes for gemm_out.
__global__ __launch_bounds__(256, 4) void attn_mfma(
    const short* __restrict__ QU, const short* __restrict__ QV,
    const short* __restrict__ Kb, const short* __restrict__ Vt,
    const short* __restrict__ POSb, short* __restrict__ CTXh,
    short* __restrict__ CTXl) {
  __shared__ float PB[64 * 128];   // 32 KB band buffer (swizzled cols)
  __shared__ short Pl[64 * 64];    // 8 KB P tile bf16 (swizzled cols)
  const int tid = threadIdx.x;
  const int w = tid >> 6;
  const int lane = tid & 63;
  const int col = lane & 15;
  const int quad = lane >> 4;
  const int m0 = blockIdx.x * 64;
  const int bh = blockIdx.y;
  const int b = bh >> 4, h = bh & 15;

  const short* QUh = QU + (size_t)bh * S_ * D_;
  const short* QVh = QV + (size_t)bh * S_ * D_;
  const short* Kh = Kb + (size_t)bh * S_ * D_;
  const short* Vh = Vt + (size_t)bh * D_ * S_;
  const short* Ph = POSb + (size_t)bh * S_ * D_;

  const int arow = m0 + 16 * w + col;
  const bf16x8 aQU = *(const bf16x8*)(QUh + (size_t)arow * D_ + quad * 8);
  const bf16x8 aQVA = *(const bf16x8*)(QVh + (size_t)arow * D_ + quad * 8);
  const bf16x8 aQVB = *(const bf16x8*)(QVh + (size_t)(arow + 1) * D_ + quad * 8);

  const f32x4 zc = {0.f, 0.f, 0.f, 0.f};
  const bf16x8 zb = {0, 0, 0, 0, 0, 0, 0, 0};
  f32x4 ctxa0 = zc, ctxa1 = zc;
  float lpart[4] = {0.f, 0.f, 0.f, 0.f};
  const int mi0 = 16 * w + 4 * quad;

  for (int ch = 0; ch < 32; ++ch) {
    const int n0 = ch * 64;
    const int dnm = n0 - m0;
    f32x4 sc[4];
#pragma unroll
    for (int j = 0; j < 4; ++j) {
      bf16x8 bk = *(const bf16x8*)(Kh + (size_t)(n0 + 16 * j + col) * D_ + quad * 8);
      sc[j] = __builtin_amdgcn_mfma_f32_16x16x32_bf16(aQU, bk, zc, 0, 0, 0);
    }
    if (dnm <= 63) {
      const int tA0 = S_ - 64 + dnm;
#pragma unroll
      for (int j = 0; j < 8; ++j) {
        const int t = tA0 + 16 * j + col;
        bf16x8 bp = *(const bf16x8*)(Ph + (long)t * D_ + quad * 8);
        if (t >= S_) bp = zb;
        f32x4 c = __builtin_amdgcn_mfma_f32_16x16x32_bf16(aQVA, bp, zc, 0, 0, 0);
#pragma unroll
        for (int r = 0; r < 4; ++r) {
          const int mi = mi0 + r;
          const int cc = (16 * j + col) ^ (((mi & 4) << 2) ^ ((mi & 3) << 3));
          PB[mi * 128 + cc] = c[r];
        }
      }
      __syncthreads();
#pragma unroll
      for (int j = 0; j < 4; ++j)
#pragma unroll
        for (int r = 0; r < 4; ++r) {
          const int mi = mi0 + r;
          const int nj = 16 * j + col;
          if (dnm + nj - mi <= 0) {
            const int idx = (nj - mi + 63) ^ (((mi & 4) << 2) ^ ((mi & 3) << 3));
            sc[j][r] += PB[mi * 128 + idx];
          }
        }
    }
    if (dnm >= -61) {
      __syncthreads();
      const int tB0 = dnm - 65;
#pragma unroll
      for (int j = 0; j < 8; ++j) {
        const int t = tB0 + 16 * j + col;
        bf16x8 bp = *(const bf16x8*)(Ph + (long)t * D_ + quad * 8);
        if (t < 0) bp = zb;
        f32x4 c = __builtin_amdgcn_mfma_f32_16x16x32_bf16(aQVB, bp, zc, 0, 0, 0);
#pragma unroll
        for (int r = 0; r < 4; ++r) {
          const int mi = mi0 + r;
          const int cc = (16 * j + col) ^ (((mi & 4) << 2) ^ ((mi & 3) << 3));
          PB[mi * 128 + cc] = c[r];
        }
      }
      __syncthreads();
#pragma unroll
      for (int j = 0; j < 4; ++j)
#pragma unroll
        for (int r = 0; r < 4; ++r) {
          const int mi = mi0 + r;
          const int nj = 16 * j + col;
          if (dnm + nj - mi >= 2) {
            const int idx = (nj - mi + 63) ^ (((mi & 4) << 2) ^ ((mi & 3) << 3));
            sc[j][r] += PB[mi * 128 + idx];
          }
        }
    }
    __syncthreads();
#pragma unroll
    for (int j = 0; j < 4; ++j)
#pragma unroll
      for (int r = 0; r < 4; ++r) {
        const float p = __expf(sc[j][r] * RSCALE);
        lpart[r] += p;
        const int mi = mi0 + r;
        const int cc = (16 * j + col) ^ ((mi & 7) << 3);
        Pl[mi * 64 + cc] = (short)f2bf(p);
      }
    __syncthreads();
    const int prow = 16 * w + col;
    const int psw = (prow & 7) << 3;
#pragma unroll
    for (int k0 = 0; k0 < 2; ++k0) {
      const bf16x8 ap = *(const bf16x8*)(&Pl[prow * 64 + ((k0 * 32 + quad * 8) ^ psw)]);
      bf16x8 bv0 = *(const bf16x8*)(Vh + (size_t)col * S_ + n0 + k0 * 32 + quad * 8);
      ctxa0 = __builtin_amdgcn_mfma_f32_16x16x32_bf16(ap, bv0, ctxa0, 0, 0, 0);
      bf16x8 bv1 = *(const bf16x8*)(Vh + (size_t)(16 + col) * S_ + n0 + k0 * 32 + quad * 8);
      ctxa1 = __builtin_amdgcn_mfma_f32_16x16x32_bf16(ap, bv1, ctxa1, 0, 0, 0);
    }
  }
#pragma unroll
  for (int r = 0; r < 4; ++r) {
    float s = lpart[r];
    s += __shfl_xor(s, 1);
    s += __shfl_xor(s, 2);
    s += __shfl_xor(s, 4);
    s += __shfl_xor(s, 8);
    lpart[r] = 1.0f / s;
  }
  const int mrow = m0 + mi0;
#pragma unroll
  for (int r = 0; r < 4; ++r) {
    const size_t obase = ((size_t)(b * S_ + mrow + r)) * C_ + h * D_;
    const float v0 = ctxa0[r] * lpart[r];
    const float v1 = ctxa1[r] * lpart[r];
    const unsigned u0 = __builtin_bit_cast(unsigned, v0) & 0xffff0000u;
    const unsigned u1 = __builtin_bit_cast(unsigned, v1) & 0xffff0000u;
    CTXh[obase + col] = (short)(u0 >> 16);
    CTXl[obase + col] = (short)f2bf(v0 - __builtin_bit_cast(float, u0));
    CTXh[obase + 16 + col] = (short)(u1 >> 16);
    CTXl[obase + 16 + col] = (short)f2bf(v1 - __builtin_bit_cast(float, u1));
  }
}

extern "C" void kernel_launch(void* const* d_in, const int* in_sizes, int n_in,
                              void* d_out, int out_size, void* d_ws, size_t ws_size,
                              hipStream_t stream) {
  (void)in_sizes; (void)n_in; (void)out_size; (void)ws_size;
  const float* q = (const float*)d_in[0];
  const float* k = (const float*)d_in[1];
  const float* v = (const float*)d_in[2];
  const float* pe = (const float*)d_in[3];
  const float* Wq = (const float*)d_in[4];
  const float* bq = (const float*)d_in[5];
  const float* Wk = (const float*)d_in[6];
  const float* bk = (const float*)d_in[7];
  const float* Wv = (const float*)d_in[8];
  const float* bv = (const float*)d_in[9];
  const float* Wp = (const float*)d_in[10];
  const float* ub = (const float*)d_in[11];
  const float* vb = (const float*)d_in[12];
  const float* Wo = (const float*)d_in[13];
  const float* bo = (const float*)d_in[14];
  float* out = (float*)d_out;

  const size_t MC = (size_t)M_ * C_;   // 2,097,152 elems
  const size_t WC = (size_t)C_ * C_;   // 262,144 elems
  short* XH = (short*)d_ws;            // [4][M][C]
  short* XL = XH + 4 * MC;
  short* WH = XL + 4 * MC;             // [5][C][C]
  short* WL = WH + 5 * WC;
  short* QUb = WL + 5 * WC;
  short* QVb = QUb + MC;
  short* Kbb = QVb + MC;
  short* Vtb = Kbb + MC;
  short* POSB = Vtb + MC;
  short* CTXh = POSB + MC;
  short* CTXl = CTXh + MC;

  split_x<<<dim3(2048, 4), 256, 0, stream>>>(q, k, v, pe, XH, XL);
  split_w<<<dim3(256, 5), 256, 0, stream>>>(Wq, Wk, Wv, Wp, Wo, WH, WL);
  proj4<<<dim3(8, 64, 4), 256, 0, stream>>>(XH, XL, WH, WL, bq, bk, bv, ub, vb,
                                            QUb, QVb, Kbb, Vtb, POSB);
  attn_mfma<<<dim3(S_ / 64, B_ * H_), 256, 0, stream>>>(QUb, QVb, Kbb, Vtb, POSB,
                                                        CTXh, CTXl);
  gemm_out<<<dim3(8, 64), 256, 0, stream>>>(CTXh, CTXl, WH, WL, bo, out);
}